// Round 6
// baseline (241.146 us; speedup 1.0000x reference)
//
#include <hip/hip_runtime.h>

typedef unsigned short ushort_t;
typedef __attribute__((ext_vector_type(8)))  short  short8;
typedef __attribute__((ext_vector_type(4)))  float  float4v;

#define N_NODES 4096
#define NHEADS  4
#define DK      128
#define ODIM    512
#define KDIM    512

__device__ __forceinline__ float bf2f(ushort_t u) {
    return __uint_as_float(((unsigned)u) << 16);
}
__device__ __forceinline__ ushort_t f2bf_rne(float f) {
    unsigned u = __float_as_uint(f);
    u += 0x7fffu + ((u >> 16) & 1u);
    return (ushort_t)(u >> 16);
}

// ---------------------------------------------------------------------------
// Kernel 0: input-dtype detector (1 = fp32 inputs).
// ---------------------------------------------------------------------------
__global__ __launch_bounds__(64) void detect_k(const ushort_t* __restrict__ Hraw,
                                               int* __restrict__ flag)
{
    const int lane = threadIdx.x;
    int cnt = 0;
    #pragma unroll
    for (int s = 0; s < 16; ++s) {
        ushort_t v = Hraw[(lane * 16 + s) * 2];
        int e = (v >> 7) & 0xFF;
        cnt += (((e >= 90) && (e <= 140)) || (v == 0)) ? 1 : 0;
    }
    #pragma unroll
    for (int off = 32; off; off >>= 1) cnt += __shfl_down(cnt, off);
    if (lane == 0) *flag = (cnt < 768) ? 1 : 0;
}

// ---------------------------------------------------------------------------
// Kernel 1: bit-pack mask = (A != 0) || (i == j).  64 MB -> 2 MB.
// ---------------------------------------------------------------------------
__global__ __launch_bounds__(256) void pack_mask_k(const int* __restrict__ A,
                                                   unsigned long long* __restrict__ P)
{
    int flat = blockIdx.x * 256 + threadIdx.x;
    int row  = flat >> 12;
    int col  = flat & 4095;
    int a    = A[flat];
    unsigned long long m = __ballot((a != 0) || (row == col));
    if ((threadIdx.x & 63) == 0) P[flat >> 6] = m;
}

// ---------------------------------------------------------------------------
// Kernel 1b: H -> bf16 (dual-dtype input), 8 elems/thread.
// ---------------------------------------------------------------------------
__global__ __launch_bounds__(256) void convh_k(const void* __restrict__ H,
                                               ushort_t* __restrict__ Hb,
                                               const int* __restrict__ flag)
{
    const int f32 = *flag;
    const size_t base = ((size_t)blockIdx.x * 256 + threadIdx.x) * 8;
    if (f32) {
        const float4v* s = (const float4v*)((const float*)H + base);
        float4v a = s[0], b = s[1];
        short8 v;
        #pragma unroll
        for (int e = 0; e < 4; ++e) {
            v[e]     = (short)f2bf_rne(a[e]);
            v[4 + e] = (short)f2bf_rne(b[e]);
        }
        *(short8*)(Hb + base) = v;
    } else {
        *(short8*)(Hb + base) = *(const short8*)((const ushort_t*)H + base);
    }
}

// ---------------------------------------------------------------------------
// Kernel 2: WT[n][k] = W[k][n] as bf16 (dual-dtype input).
// ---------------------------------------------------------------------------
__global__ __launch_bounds__(256) void transpose_w_k(const void* __restrict__ W,
                                                     ushort_t* __restrict__ WT,
                                                     const int* __restrict__ flag)
{
    __shared__ ushort_t lt[64][72];
    const int f32 = *flag;
    const int tid = threadIdx.x;
    const int ti = blockIdx.x >> 3, tj = blockIdx.x & 7;
    const int r = tid >> 2, c2 = tid & 3;
    const size_t eo = (size_t)(ti * 64 + r) * KDIM + tj * 64 + c2 * 16;
    if (f32) {
        const float4v* src = (const float4v*)((const float*)W + eo);
        float4v f0 = src[0], f1 = src[1], f2 = src[2], f3 = src[3];
        #pragma unroll
        for (int e = 0; e < 4; ++e) {
            lt[r][c2 * 16 +  0 + e] = f2bf_rne(f0[e]);
            lt[r][c2 * 16 +  4 + e] = f2bf_rne(f1[e]);
            lt[r][c2 * 16 +  8 + e] = f2bf_rne(f2[e]);
            lt[r][c2 * 16 + 12 + e] = f2bf_rne(f3[e]);
        }
    } else {
        const short8* src = (const short8*)((const ushort_t*)W + eo);
        short8 v0 = src[0];
        short8 v1 = src[1];
        *(short8*)&lt[r][c2 * 16]     = v0;
        *(short8*)&lt[r][c2 * 16 + 8] = v1;
    }
    __syncthreads();
    #pragma unroll
    for (int itr = 0; itr < 2; ++itr) {
        int idx = itr * 256 + tid;
        int n = idx >> 3, c = idx & 7;
        short8 vv;
        #pragma unroll
        for (int e = 0; e < 8; ++e) vv[e] = (short)lt[c * 8 + e][n];
        *(short8*)(WT + (size_t)(tj * 64 + n) * KDIM + ti * 64 + c * 8) = vv;
    }
}

// ---------------------------------------------------------------------------
// Kernel 3: WhT[n][i] = (Hb @ W)[i][n].  16x16x32 MFMA, bf16 A direct loads.
// ---------------------------------------------------------------------------
__global__ __launch_bounds__(256) void gemm_wht_k(const ushort_t* __restrict__ Hb,
                                                  const ushort_t* __restrict__ WT,
                                                  ushort_t* __restrict__ WhT)
{
    __shared__ ushort_t lt[64][72];
    const int tid  = threadIdx.x;
    const int lane = tid & 63;
    const int wid  = tid >> 6;
    const int quad = lane >> 4;
    const int l15  = lane & 15;
    const int bm = blockIdx.x >> 3, bn = blockIdx.x & 7;
    const int i0 = bm * 64, n0 = bn * 64;

    const short8* ap  = (const short8*)(Hb + (size_t)(i0 + wid * 16 + l15) * KDIM) + quad;
    const short8* bp0 = (const short8*)(WT + (size_t)(n0 +  0 + l15) * KDIM) + quad;
    const short8* bp1 = (const short8*)(WT + (size_t)(n0 + 16 + l15) * KDIM) + quad;
    const short8* bp2 = (const short8*)(WT + (size_t)(n0 + 32 + l15) * KDIM) + quad;
    const short8* bp3 = (const short8*)(WT + (size_t)(n0 + 48 + l15) * KDIM) + quad;

    float4v acc0, acc1, acc2, acc3;
    #pragma unroll
    for (int e = 0; e < 4; ++e) { acc0[e] = 0.f; acc1[e] = 0.f; acc2[e] = 0.f; acc3[e] = 0.f; }

    #pragma unroll 4
    for (int k8 = 0; k8 < 64; k8 += 4) {
        short8 a = ap[k8];
        acc0 = __builtin_amdgcn_mfma_f32_16x16x32_bf16(a, bp0[k8], acc0, 0, 0, 0);
        acc1 = __builtin_amdgcn_mfma_f32_16x16x32_bf16(a, bp1[k8], acc1, 0, 0, 0);
        acc2 = __builtin_amdgcn_mfma_f32_16x16x32_bf16(a, bp2[k8], acc2, 0, 0, 0);
        acc3 = __builtin_amdgcn_mfma_f32_16x16x32_bf16(a, bp3[k8], acc3, 0, 0, 0);
    }

    #pragma unroll
    for (int r = 0; r < 4; ++r) {
        int m = wid * 16 + quad * 4 + r;
        lt[ 0 + l15][m] = f2bf_rne(acc0[r]);
        lt[16 + l15][m] = f2bf_rne(acc1[r]);
        lt[32 + l15][m] = f2bf_rne(acc2[r]);
        lt[48 + l15][m] = f2bf_rne(acc3[r]);
    }
    __syncthreads();
    #pragma unroll
    for (int itr = 0; itr < 2; ++itr) {
        int idx = itr * 256 + tid;
        int n = idx >> 3, c = idx & 7;
        short8 v = *(const short8*)&lt[n][c * 8];
        *(short8*)(WhT + (size_t)(n0 + n) * N_NODES + i0 + c * 8) = v;
    }
}

// Fallback gemm (dual-dtype H) if ws is too small for Hb.
__global__ __launch_bounds__(256) void gemm_wht_dual_k(const void* __restrict__ H,
                                                       const ushort_t* __restrict__ WT,
                                                       ushort_t* __restrict__ WhT,
                                                       const int* __restrict__ flag)
{
    __shared__ ushort_t lt[64][72];
    const int f32 = *flag;
    const int tid  = threadIdx.x;
    const int lane = tid & 63;
    const int wid  = tid >> 6;
    const int quad = lane >> 4;
    const int l15  = lane & 15;
    const int bm = blockIdx.x >> 3, bn = blockIdx.x & 7;
    const int i0 = bm * 64, n0 = bn * 64;

    const size_t aoff = (size_t)(i0 + wid * 16 + l15) * KDIM + quad * 8;
    const short8* bp0 = (const short8*)(WT + (size_t)(n0 +  0 + l15) * KDIM) + quad;
    const short8* bp1 = (const short8*)(WT + (size_t)(n0 + 16 + l15) * KDIM) + quad;
    const short8* bp2 = (const short8*)(WT + (size_t)(n0 + 32 + l15) * KDIM) + quad;
    const short8* bp3 = (const short8*)(WT + (size_t)(n0 + 48 + l15) * KDIM) + quad;

    float4v acc0, acc1, acc2, acc3;
    #pragma unroll
    for (int e = 0; e < 4; ++e) { acc0[e] = 0.f; acc1[e] = 0.f; acc2[e] = 0.f; acc3[e] = 0.f; }

    #pragma unroll 4
    for (int k8 = 0; k8 < 64; k8 += 4) {
        short8 a;
        if (f32) {
            const float4v* fp = (const float4v*)((const float*)H + aoff + (size_t)k8 * 8);
            float4v x0 = fp[0], x1 = fp[1];
            #pragma unroll
            for (int e = 0; e < 4; ++e) {
                a[e]     = (short)f2bf_rne(x0[e]);
                a[4 + e] = (short)f2bf_rne(x1[e]);
            }
        } else {
            a = *(const short8*)((const ushort_t*)H + aoff + (size_t)k8 * 8);
        }
        acc0 = __builtin_amdgcn_mfma_f32_16x16x32_bf16(a, bp0[k8], acc0, 0, 0, 0);
        acc1 = __builtin_amdgcn_mfma_f32_16x16x32_bf16(a, bp1[k8], acc1, 0, 0, 0);
        acc2 = __builtin_amdgcn_mfma_f32_16x16x32_bf16(a, bp2[k8], acc2, 0, 0, 0);
        acc3 = __builtin_amdgcn_mfma_f32_16x16x32_bf16(a, bp3[k8], acc3, 0, 0, 0);
    }

    #pragma unroll
    for (int r = 0; r < 4; ++r) {
        int m = wid * 16 + quad * 4 + r;
        lt[ 0 + l15][m] = f2bf_rne(acc0[r]);
        lt[16 + l15][m] = f2bf_rne(acc1[r]);
        lt[32 + l15][m] = f2bf_rne(acc2[r]);
        lt[48 + l15][m] = f2bf_rne(acc3[r]);
    }
    __syncthreads();
    #pragma unroll
    for (int itr = 0; itr < 2; ++itr) {
        int idx = itr * 256 + tid;
        int n = idx >> 3, c = idx & 7;
        short8 v = *(const short8*)&lt[n][c * 8];
        *(short8*)(WhT + (size_t)(n0 + n) * N_NODES + i0 + c * 8) = v;
    }
}

// ---------------------------------------------------------------------------
// Kernel 4: sl[h][i], sr[h][i] from WhT (bf16) and a_l/a_r (dual-dtype).
// ---------------------------------------------------------------------------
__global__ __launch_bounds__(256) void slsr_k(const ushort_t* __restrict__ WhT,
                                              const void* __restrict__ al,
                                              const void* __restrict__ ar,
                                              float* __restrict__ sl,
                                              float* __restrict__ sr,
                                              const int* __restrict__ flag)
{
    const int f32 = *flag;
    const int b = blockIdx.x;
    const int h = b >> 4;
    const int i = ((b & 15) << 8) + threadIdx.x;
    float asl = 0.f, asr = 0.f;
    #pragma unroll 8
    for (int d = 0; d < DK; ++d) {
        float v  = bf2f(WhT[(size_t)(h * DK + d) * N_NODES + i]);
        float av = f32 ? ((const float*)al)[h * DK + d] : bf2f(((const ushort_t*)al)[h * DK + d]);
        float bv = f32 ? ((const float*)ar)[h * DK + d] : bf2f(((const ushort_t*)ar)[h * DK + d]);
        asl += v * av;
        asr += v * bv;
    }
    sl[h * N_NODES + i] = asl;
    sr[h * N_NODES + i] = asr;
}

// ---------------------------------------------------------------------------
// Kernel 5 v4: attention, barrier-free main loop + register-ping-pong V
// prefetch (load->use distance ~2 windows >> L2 latency) + denominator via
// MFMA-with-ones (same C-layout as acc -> shuffle-free epilogue).
// Block = (32-row i-tile, head), 4 waves; wave = one j-quarter (1024 j).
// ---------------------------------------------------------------------------
__global__ __launch_bounds__(256, 2) void attn_k(const ushort_t* __restrict__ WhT,
                                                 const unsigned* __restrict__ Apack,
                                                 const float* __restrict__ sl,
                                                 const float* __restrict__ sr,
                                                 void* __restrict__ out,
                                                 const int* __restrict__ flag)
{
    __shared__ float    srs[N_NODES];        // 16 KB  head's sr
    __shared__ unsigned mbuf[32][128];       // 16 KB  mask rows
    __shared__ float    red[2][32][128];     // 32 KB  epilogue merge
    __shared__ float    lsum[4][32];         // 512 B  denom partials

    const int f32  = *flag;
    const int tid  = threadIdx.x;
    const int lane = tid & 63;
    const int wq   = tid >> 6;               // j-quarter 0..3
    const int quad = lane >> 4;
    const int l15  = lane & 15;
    const int h    = blockIdx.x & 3;
    const int i0   = (blockIdx.x >> 2) << 5; // 32-row tile

    for (int j = tid; j < N_NODES; j += 256) srs[j] = sr[h * N_NODES + j];
    for (int t = tid; t < 32 * 128; t += 256) {
        int r = t >> 7, c = t & 127;
        mbuf[r][c] = Apack[(size_t)(i0 + r) * 128 + c];
    }
    const float slv0 = sl[h * N_NODES + i0 + l15];
    const float slv1 = sl[h * N_NODES + i0 + 16 + l15];
    __syncthreads();                          // srs+mbuf ready

    const float C1 = 1.44269504f;             // log2(e)
    const float C2 = 0.2f * 1.44269504f;

    float4v acc[2][8];
    #pragma unroll
    for (int mg = 0; mg < 2; ++mg)
        #pragma unroll
        for (int nt = 0; nt < 8; ++nt)
            #pragma unroll
            for (int e = 0; e < 4; ++e) acc[mg][nt][e] = 0.f;
    float4v accden0, accden1;
    #pragma unroll
    for (int e = 0; e < 4; ++e) { accden0[e] = 0.f; accden1[e] = 0.f; }

    short8 ones;
    #pragma unroll
    for (int e = 0; e < 8; ++e) ones[e] = (short)0x3F80;   // bf16 1.0

    // B-frag base: lane holds V^T[d = nt*16+l15][j = quad*8 .. +7]
    const ushort_t* vb = WhT + (size_t)(h * DK + l15) * N_NODES + wq * 1024 + quad * 8;

    short8 bfA[8][2], bfB[8][2];
    short8 pf0[2], pf1[2];

    #define PREFETCH(BUF, JL)                                                          \
        {   _Pragma("unroll")                                                          \
            for (int nt = 0; nt < 8; ++nt) {                                           \
                BUF[nt][0] = *(const short8*)(vb + (size_t)nt * 16 * N_NODES + (JL));  \
                BUF[nt][1] = *(const short8*)(vb + (size_t)nt * 16 * N_NODES + (JL) + 32); \
            }                                                                          \
        }

    #define SOFTMAX_WIN(JL)                                                            \
        {   const int j0_ = wq * 1024 + (JL);                                          \
            const int mc_ = j0_ >> 5;                                                  \
            const unsigned wa0 = mbuf[l15][mc_],      wa1 = mbuf[l15][mc_ + 1];        \
            const unsigned wb0 = mbuf[16 + l15][mc_], wb1 = mbuf[16 + l15][mc_ + 1];   \
            _Pragma("unroll")                                                          \
            for (int s = 0; s < 2; ++s) {                                              \
                const float* sp_ = &srs[j0_ + s * 32 + quad * 8];                      \
                const float4v s0_ = *(const float4v*)sp_;                              \
                const float4v s1_ = *(const float4v*)(sp_ + 4);                        \
                const unsigned wa = s ? wa1 : wa0;                                     \
                const unsigned wb = s ? wb1 : wb0;                                     \
                _Pragma("unroll")                                                      \
                for (int jj = 0; jj < 8; ++jj) {                                       \
                    float srj = (jj < 4) ? s0_[jj] : s1_[jj - 4];                      \
                    int bit = quad * 8 + jj;                                           \
                    float x0 = slv0 + srj;                                             \
                    float t0 = fmaxf(x0 * C1, x0 * C2);                                \
                    t0 = ((wa >> bit) & 1u) ? t0 : -1e30f;                             \
                    pf0[s][jj] = (short)(ushort_t)(__float_as_uint(__builtin_amdgcn_exp2f(t0)) >> 16); \
                    float x1 = slv1 + srj;                                             \
                    float t1 = fmaxf(x1 * C1, x1 * C2);                                \
                    t1 = ((wb >> bit) & 1u) ? t1 : -1e30f;                             \
                    pf1[s][jj] = (short)(ushort_t)(__float_as_uint(__builtin_amdgcn_exp2f(t1)) >> 16); \
                }                                                                      \
            }                                                                          \
        }

    #define MFMA_WIN(BUF)                                                              \
        {   _Pragma("unroll")                                                          \
            for (int nt = 0; nt < 8; ++nt) {                                           \
                acc[0][nt] = __builtin_amdgcn_mfma_f32_16x16x32_bf16(pf0[0], BUF[nt][0], acc[0][nt], 0, 0, 0); \
                acc[0][nt] = __builtin_amdgcn_mfma_f32_16x16x32_bf16(pf0[1], BUF[nt][1], acc[0][nt], 0, 0, 0); \
                acc[1][nt] = __builtin_amdgcn_mfma_f32_16x16x32_bf16(pf1[0], BUF[nt][0], acc[1][nt], 0, 0, 0); \
                acc[1][nt] = __builtin_amdgcn_mfma_f32_16x16x32_bf16(pf1[1], BUF[nt][1], acc[1][nt], 0, 0, 0); \
            }                                                                          \
            accden0 = __builtin_amdgcn_mfma_f32_16x16x32_bf16(pf0[0], ones, accden0, 0, 0, 0); \
            accden0 = __builtin_amdgcn_mfma_f32_16x16x32_bf16(pf0[1], ones, accden0, 0, 0, 0); \
            accden1 = __builtin_amdgcn_mfma_f32_16x16x32_bf16(pf1[0], ones, accden1, 0, 0, 0); \
            accden1 = __builtin_amdgcn_mfma_f32_16x16x32_bf16(pf1[1], ones, accden1, 0, 0, 0); \
        }

    PREFETCH(bfA, 0)
    #pragma unroll 1
    for (int it = 0; it < 16; it += 2) {
        PREFETCH(bfB, (it + 1) * 64)          // issued ~2 windows before use
        SOFTMAX_WIN(it * 64)
        MFMA_WIN(bfA)
        if (it + 2 < 16) PREFETCH(bfA, (it + 2) * 64)
        SOFTMAX_WIN((it + 1) * 64)
        MFMA_WIN(bfB)
    }

    // ---- epilogue: accden is already per-row (C-layout) -> no shuffles ----
    if (l15 == 0) {
        #pragma unroll
        for (int r = 0; r < 4; ++r) {
            lsum[wq][quad * 4 + r]      = accden0[r];
            lsum[wq][16 + quad * 4 + r] = accden1[r];
        }
    }
    if (wq >= 2) {
        #pragma unroll
        for (int mg = 0; mg < 2; ++mg)
            #pragma unroll
            for (int nt = 0; nt < 8; ++nt)
                #pragma unroll
                for (int r = 0; r < 4; ++r)
                    red[wq - 2][mg * 16 + quad * 4 + r][nt * 16 + l15] = acc[mg][nt][r];
    }
    __syncthreads();
    if (wq < 2) {
        #pragma unroll
        for (int mg = 0; mg < 2; ++mg)
            #pragma unroll
            for (int nt = 0; nt < 8; ++nt)
                #pragma unroll
                for (int r = 0; r < 4; ++r)
                    acc[mg][nt][r] += red[wq][mg * 16 + quad * 4 + r][nt * 16 + l15];
    }
    __syncthreads();
    if (wq == 1) {
        #pragma unroll
        for (int mg = 0; mg < 2; ++mg)
            #pragma unroll
            for (int nt = 0; nt < 8; ++nt)
                #pragma unroll
                for (int r = 0; r < 4; ++r)
                    red[0][mg * 16 + quad * 4 + r][nt * 16 + l15] = acc[mg][nt][r];
    }
    __syncthreads();
    if (wq == 0) {
        #pragma unroll
        for (int mg = 0; mg < 2; ++mg) {
            float linv[4];
            #pragma unroll
            for (int r = 0; r < 4; ++r) {
                int rowi = mg * 16 + quad * 4 + r;
                float den = lsum[0][rowi] + lsum[1][rowi] + lsum[2][rowi] + lsum[3][rowi];
                linv[r] = 1.0f / fmaxf(den, 1e-37f);
            }
            #pragma unroll
            for (int nt = 0; nt < 8; ++nt)
                #pragma unroll
                for (int r = 0; r < 4; ++r) {
                    int rowi = mg * 16 + quad * 4 + r;
                    float v = (acc[mg][nt][r] + red[0][rowi][nt * 16 + l15]) * linv[r];
                    float e = __builtin_amdgcn_exp2f(v * C1) - 1.0f;
                    float o = (v > 0.f) ? v : e;
                    size_t oidx = (size_t)(i0 + rowi) * ODIM + h * DK + nt * 16 + l15;
                    if (f32) ((float*)out)[oidx] = o;
                    else     ((ushort_t*)out)[oidx] = f2bf_rne(o);
                }
        }
    }
    #undef PREFETCH
    #undef SOFTMAX_WIN
    #undef MFMA_WIN
}

// ---------------------------------------------------------------------------
extern "C" void kernel_launch(void* const* d_in, const int* in_sizes, int n_in,
                              void* d_out, int out_size, void* d_ws, size_t ws_size,
                              hipStream_t stream)
{
    const void* H  = d_in[0];
    const int*  A  = (const int*)d_in[1];
    const void* W  = d_in[2];
    const void* al = d_in[3];
    const void* ar = d_in[4];

    if (ws_size < (7u << 20)) return;

    char* ws = (char*)d_ws;
    ushort_t* WhT   = (ushort_t*)ws;                                    // 4 MB
    unsigned long long* Apack = (unsigned long long*)(ws + (4u << 20)); // 2 MB
    ushort_t* WT    = (ushort_t*)(ws + (6u << 20));                     // 512 KB
    float*    sl    = (float*)(ws + (6u << 20) + (512u << 10));         // 64 KB
    float*    sr    = (float*)(ws + (6u << 20) + (576u << 10));         // 64 KB
    int*      flag  = (int*)(ws + (6u << 20) + (640u << 10));           // 4 B
    ushort_t* Hb    = (ushort_t*)(ws + (7u << 20));                     // 4 MB (optional)
    const bool have_hb = ws_size >= (11u << 20);

    detect_k    <<<1,     64,  0, stream>>>((const ushort_t*)H, flag);
    pack_mask_k <<<65536, 256, 0, stream>>>(A, Apack);
    transpose_w_k<<<64,   256, 0, stream>>>(W, WT, flag);
    if (have_hb) {
        convh_k   <<<1024, 256, 0, stream>>>(H, Hb, flag);
        gemm_wht_k<<<512,  256, 0, stream>>>(Hb, WT, WhT);
    } else {
        gemm_wht_dual_k<<<512, 256, 0, stream>>>(H, WT, WhT, flag);
    }
    slsr_k      <<<64,    256, 0, stream>>>(WhT, al, ar, sl, sr, flag);
    attn_k      <<<512,   256, 0, stream>>>(WhT, (const unsigned*)Apack, sl, sr, (void*)d_out, flag);
}